// Round 1
// baseline (621.671 us; speedup 1.0000x reference)
//
#include <hip/hip_runtime.h>
#include <math.h>

#define IMG_W   800
#define IMG_PIX (IMG_W * IMG_W)
#define NEDGE   6000
#define NSRC    4
#define NVIEW   5
// d_out layout (floats):
//   sim loss : [0, NSRC*NEDGE)
//   mask     : [NSRC*NEDGE, 2*NSRC*NEDGE)
//   black    : [2*NSRC*NEDGE, 2*NSRC*NEDGE + NEDGE)
//   p2d1     : [HDR, HDR + 2P)
//   p2d2     : [HDR + 2P, HDR + 10P)
#define HDR (2 * NSRC * NEDGE + NEDGE) // 54000

__device__ __forceinline__ float bilin(const float* __restrict__ im, float u, float v) {
    float x = u * (float)IMG_W - 0.5f;
    float y = v * (float)IMG_W - 0.5f;
    float xf = floorf(x), yf = floorf(y);
    float wx = x - xf, wy = y - yf;
    int x0 = (int)xf;
    int y0 = (int)yf;
    x0 = max(0, min(IMG_W - 1, x0));
    y0 = max(0, min(IMG_W - 1, y0));
    int x1 = min(IMG_W - 1, x0 + 1);
    int y1 = min(IMG_W - 1, y0 + 1);
    float v00 = im[y0 * IMG_W + x0];
    float v01 = im[y0 * IMG_W + x1];
    float v10 = im[y1 * IMG_W + x0];
    float v11 = im[y1 * IMG_W + x1];
    return (v00 * (1.f - wx) + v01 * wx) * (1.f - wy)
         + (v10 * (1.f - wx) + v11 * wx) * wy;
}

// Kernel A: per-edge, per-view projection params; also init accumulators/mask in d_out.
__global__ void edge_params(const float* __restrict__ sp,
                            const float* __restrict__ epnt,
                            const float* __restrict__ K,
                            const float* __restrict__ T,
                            float2* __restrict__ prm,
                            float* __restrict__ out) {
    int e = blockIdx.x * blockDim.x + threadIdx.x;
    if (e >= NEDGE) return;
    float sx = sp[3 * e], sy = sp[3 * e + 1], sz = sp[3 * e + 2];
    float ex = epnt[3 * e], ey = epnt[3 * e + 1], ez = epnt[3 * e + 2];
    for (int v = 0; v < NVIEW; ++v) {
        float as, bs, cs, ae, be, ce;
        if (v == 0) {
            as = K[0] * sx + K[1] * sy + K[2] * sz;
            bs = K[3] * sx + K[4] * sy + K[5] * sz;
            cs = K[6] * sx + K[7] * sy + K[8] * sz;
            ae = K[0] * ex + K[1] * ey + K[2] * ez;
            be = K[3] * ex + K[4] * ey + K[5] * ez;
            ce = K[6] * ex + K[7] * ey + K[8] * ez;
        } else {
            const float* t = T + (v - 1) * 12;
            as = t[0] * sx + t[1] * sy + t[2] * sz + t[3];
            bs = t[4] * sx + t[5] * sy + t[6] * sz + t[7];
            cs = t[8] * sx + t[9] * sy + t[10] * sz + t[11];
            ae = t[0] * ex + t[1] * ey + t[2] * ez + t[3];
            be = t[4] * ex + t[5] * ey + t[6] * ez + t[7];
            ce = t[8] * ex + t[9] * ey + t[10] * ez + t[11];
        }
        float u0 = as / (cs + 1e-6f);
        float w0 = bs / (cs + 1e-6f);
        float u1 = ae / (ce + 1e-6f);
        float w1 = be / (ce + 1e-6f);
        float dx = u1 - u0, dy = w1 - w0;
        // cross([dx,dy,0],[0,0,1]) = (dy, -dx, 0)
        float cxx = dy, cyy = -dx;
        float nrm = sqrtf(cxx * cxx + cyy * cyy);
        float inv = 1.f / (nrm + 1e-6f) * (10.0f / (float)IMG_W);
        prm[(e * NVIEW + v) * 3 + 0] = make_float2(u0, w0);
        prm[(e * NVIEW + v) * 3 + 1] = make_float2(dx, dy);
        prm[(e * NVIEW + v) * 3 + 2] = make_float2(cxx * inv, cyy * inv);
    }
    // init output accumulators (d_out is poisoned 0xAA before every launch)
    for (int s = 0; s < NSRC; ++s) {
        out[s * NEDGE + e] = 0.f;               // sim loss accum
        out[NSRC * NEDGE + s * NEDGE + e] = 1.f; // mask (segment_min of vm)
    }
    out[2 * NSRC * NEDGE + e] = 0.f;            // black count accum
}

// Kernel B: per-point sampling + wave-aggregated segment sums.
__global__ void points_kernel(const float* __restrict__ cx,
                              const float* __restrict__ cy,
                              const int* __restrict__ eidx,
                              const float* __restrict__ imgs,
                              const float2* __restrict__ prm,
                              float* __restrict__ out,
                              int P) {
    int i = blockIdx.x * blockDim.x + threadIdx.x;
    bool active = i < P;
    int e = -1;
    float d2a = 0.f, d2b = 0.f, d2c = 0.f, d2d = 0.f, blackf = 0.f;
    if (active) {
        e = eidx[i];
        float x = cx[i], y = cy[i];
        const float2* pe = prm + e * (NVIEW * 3);
        // view 0 (reference image)
        float2 p0 = pe[0], dr = pe[1], up = pe[2];
        float px = dr.x * x + up.x * y + p0.x;
        float py = dr.y * x + up.y * y + p0.y;
        bool vm1 = (px > 0.f) && (px < 1.f) && (py > 0.f) && (py < 1.f);
        px = fminf(fmaxf(px, 0.f), 0.999999f);
        py = fminf(fmaxf(py, 0.f), 0.999999f);
        ((float2*)(out + HDR))[i] = make_float2(px, py);
        float s1 = bilin(imgs, px, py);
        blackf = (s1 < 0.01f) ? 1.f : 0.f;
        float2* p2out = (float2*)(out + HDR + 2 * (size_t)P);
        float d2[NSRC];
#pragma unroll
        for (int s = 0; s < NSRC; ++s) {
            float2 q0 = pe[(s + 1) * 3], qd = pe[(s + 1) * 3 + 1], qu = pe[(s + 1) * 3 + 2];
            float qx = qd.x * x + qu.x * y + q0.x;
            float qy = qd.y * x + qu.y * y + q0.y;
            bool vm2 = (qx > 0.f) && (qx < 1.f) && (qy > 0.f) && (qy < 1.f);
            qx = fminf(fmaxf(qx, 0.f), 0.999999f);
            qy = fminf(fmaxf(qy, 0.f), 0.999999f);
            p2out[(size_t)s * P + i] = make_float2(qx, qy);
            float sv = bilin(imgs + (s + 1) * IMG_PIX, qx, qy);
            float d = sv - s1;
            d2[s] = d * d;
            if (!(vm1 && vm2)) out[NSRC * NEDGE + s * NEDGE + e] = 0.f; // all writers write 0
        }
        d2a = d2[0]; d2b = d2[1]; d2c = d2[2]; d2d = d2[3];
    }
    // wave-level aggregation: consecutive points nearly always share an edge
    int lane = threadIdx.x & 63;
    bool uni = __all(e == __shfl(e, 0));
    if (uni) {
#pragma unroll
        for (int off = 32; off > 0; off >>= 1) {
            d2a += __shfl_down(d2a, off);
            d2b += __shfl_down(d2b, off);
            d2c += __shfl_down(d2c, off);
            d2d += __shfl_down(d2d, off);
            blackf += __shfl_down(blackf, off);
        }
        if (lane == 0 && e >= 0) {
            atomicAdd(&out[0 * NEDGE + e], d2a);
            atomicAdd(&out[1 * NEDGE + e], d2b);
            atomicAdd(&out[2 * NEDGE + e], d2c);
            atomicAdd(&out[3 * NEDGE + e], d2d);
            if (blackf != 0.f) atomicAdd(&out[2 * NSRC * NEDGE + e], blackf);
        }
    } else if (active) {
        atomicAdd(&out[0 * NEDGE + e], d2a);
        atomicAdd(&out[1 * NEDGE + e], d2b);
        atomicAdd(&out[2 * NEDGE + e], d2c);
        atomicAdd(&out[3 * NEDGE + e], d2d);
        if (blackf != 0.f) atomicAdd(&out[2 * NSRC * NEDGE + e], 1.f);
    }
}

// Kernel C: finalize (divide by per-edge count; black-area threshold).
__global__ void finalize_kernel(const int* __restrict__ npe, float* __restrict__ out) {
    int e = blockIdx.x * blockDim.x + threadIdx.x;
    if (e >= NEDGE) return;
    float cnt = (float)npe[e];
#pragma unroll
    for (int s = 0; s < NSRC; ++s)
        out[s * NEDGE + e] = out[s * NEDGE + e] / cnt;
    float bc = out[2 * NSRC * NEDGE + e];
    out[2 * NSRC * NEDGE + e] = (bc / cnt > 0.5f) ? 1.f : 0.f;
}

extern "C" void kernel_launch(void* const* d_in, const int* in_sizes, int n_in,
                              void* d_out, int out_size, void* d_ws, size_t ws_size,
                              hipStream_t stream) {
    const float* start = (const float*)d_in[0];
    const float* endp  = (const float*)d_in[1];
    const float* imgs  = (const float*)d_in[2];
    const float* trans = (const float*)d_in[3];
    const float* K     = (const float*)d_in[4];
    const float* cxs   = (const float*)d_in[5];
    const float* cys   = (const float*)d_in[6];
    const int*   eidx  = (const int*)d_in[7];
    const int*   npe   = (const int*)d_in[8];
    int P = in_sizes[5];

    float2* prm = (float2*)d_ws; // NEDGE*NVIEW*3 float2 = 720 KB

    float* out = (float*)d_out;
    edge_params<<<(NEDGE + 255) / 256, 256, 0, stream>>>(start, endp, K, trans, prm, out);
    points_kernel<<<(P + 255) / 256, 256, 0, stream>>>(cxs, cys, eidx, imgs, prm, out, P);
    finalize_kernel<<<(NEDGE + 255) / 256, 256, 0, stream>>>(npe, out);
}

// Round 2
// 583.092 us; speedup vs baseline: 1.0662x; 1.0662x over previous
//
#include <hip/hip_runtime.h>
#include <math.h>

#define IMG_W   800
#define IMG_PIX (IMG_W * IMG_W)
#define NEDGE   6000
#define NSRC    4
#define NVIEW   5
// d_out layout (floats):
//   sim loss : [0, NSRC*NEDGE)
//   mask     : [NSRC*NEDGE, 2*NSRC*NEDGE)
//   black    : [2*NSRC*NEDGE, 2*NSRC*NEDGE + NEDGE)
//   p2d1     : [HDR, HDR + 2P)
//   p2d2     : [HDR + 2P, HDR + 10P)
#define HDR (2 * NSRC * NEDGE + NEDGE) // 54000

typedef float vf2 __attribute__((ext_vector_type(2)));

// 8-byte image-row pair, only 4-byte aligned (multi-dword global loads need
// just dword alignment on CDNA).
struct __attribute__((packed, aligned(4))) f2u { float a, b; };

__device__ __forceinline__ f2u ld2(const float* __restrict__ p) {
    return *(const f2u*)p;
}

__device__ __forceinline__ void nts2(float* p, float a, float b) {
    vf2 v; v.x = a; v.y = b;
    __builtin_nontemporal_store(v, (vf2*)p);
}

// Kernel A: per-edge, per-view projection params (packed 2x float4 per view);
// also init accumulators/mask in d_out (poisoned 0xAA each launch).
__global__ void edge_params(const float* __restrict__ sp,
                            const float* __restrict__ epnt,
                            const float* __restrict__ K,
                            const float* __restrict__ T,
                            float4* __restrict__ prm,
                            float* __restrict__ out) {
    int e = blockIdx.x * blockDim.x + threadIdx.x;
    if (e >= NEDGE) return;
    float sx = sp[3 * e], sy = sp[3 * e + 1], sz = sp[3 * e + 2];
    float ex = epnt[3 * e], ey = epnt[3 * e + 1], ez = epnt[3 * e + 2];
    for (int v = 0; v < NVIEW; ++v) {
        float as, bs, cs, ae, be, ce;
        if (v == 0) {
            as = K[0] * sx + K[1] * sy + K[2] * sz;
            bs = K[3] * sx + K[4] * sy + K[5] * sz;
            cs = K[6] * sx + K[7] * sy + K[8] * sz;
            ae = K[0] * ex + K[1] * ey + K[2] * ez;
            be = K[3] * ex + K[4] * ey + K[5] * ez;
            ce = K[6] * ex + K[7] * ey + K[8] * ez;
        } else {
            const float* t = T + (v - 1) * 12;
            as = t[0] * sx + t[1] * sy + t[2] * sz + t[3];
            bs = t[4] * sx + t[5] * sy + t[6] * sz + t[7];
            cs = t[8] * sx + t[9] * sy + t[10] * sz + t[11];
            ae = t[0] * ex + t[1] * ey + t[2] * ez + t[3];
            be = t[4] * ex + t[5] * ey + t[6] * ez + t[7];
            ce = t[8] * ex + t[9] * ey + t[10] * ez + t[11];
        }
        float u0 = as / (cs + 1e-6f);
        float w0 = bs / (cs + 1e-6f);
        float u1 = ae / (ce + 1e-6f);
        float w1 = be / (ce + 1e-6f);
        float dx = u1 - u0, dy = w1 - w0;
        // cross([dx,dy,0],[0,0,1]) = (dy, -dx, 0)
        float cxx = dy, cyy = -dx;
        float nrm = sqrtf(cxx * cxx + cyy * cyy);
        float inv = 1.f / (nrm + 1e-6f) * (10.0f / (float)IMG_W);
        prm[(e * NVIEW + v) * 2 + 0] = make_float4(u0, w0, dx, dy);
        prm[(e * NVIEW + v) * 2 + 1] = make_float4(cxx * inv, cyy * inv, 0.f, 0.f);
    }
    for (int s = 0; s < NSRC; ++s) {
        out[s * NEDGE + e] = 0.f;                // sim loss accum
        out[NSRC * NEDGE + s * NEDGE + e] = 1.f; // mask (segment_min of vm)
    }
    out[2 * NSRC * NEDGE + e] = 0.f;             // black count accum
}

// Kernel B: per-point sampling + wave-aggregated segment sums.
__global__ void __launch_bounds__(256)
points_kernel(const float* __restrict__ cx,
              const float* __restrict__ cy,
              const int* __restrict__ eidx,
              const float* __restrict__ imgs,
              const float4* __restrict__ prm,
              float* __restrict__ out,
              int P) {
    int i = blockIdx.x * blockDim.x + threadIdx.x;
    bool active = i < P;
    int e = -1;
    float d2a = 0.f, d2b = 0.f, d2c = 0.f, d2d = 0.f, blackf = 0.f;
    if (active) {
        e = __builtin_nontemporal_load(&eidx[i]);
        float x = __builtin_nontemporal_load(&cx[i]);
        float y = __builtin_nontemporal_load(&cy[i]);
        const float4* pe = prm + e * (NVIEW * 2);

        // ---- stage 1: coords for all 5 views ----
        float px[NVIEW], py[NVIEW];
        bool vm[NVIEW];
#pragma unroll
        for (int v = 0; v < NVIEW; ++v) {
            float4 A = pe[2 * v];       // p0x p0y drx dry
            float4 B = pe[2 * v + 1];   // upx upy - -
            float ux = A.z * x + B.x * y + A.x;
            float uy = A.w * x + B.y * y + A.y;
            vm[v] = (ux > 0.f) && (ux < 1.f) && (uy > 0.f) && (uy < 1.f);
            px[v] = fminf(fmaxf(ux, 0.f), 0.999999f);
            py[v] = fminf(fmaxf(uy, 0.f), 0.999999f);
        }

        // ---- stage 2: p2d outputs (non-temporal; pure streaming) ----
        nts2(out + HDR + 2 * (size_t)i, px[0], py[0]);
        float* p2base = out + HDR + 2 * (size_t)P;
#pragma unroll
        for (int s = 0; s < NSRC; ++s)
            nts2(p2base + 2 * ((size_t)s * P + i), px[s + 1], py[s + 1]);

        // ---- stage 3: issue all 10 row-pair gathers ----
        f2u r0[NVIEW], r1[NVIEW];
        float wx[NVIEW], wy[NVIEW];
        bool hi[NVIEW];
#pragma unroll
        for (int v = 0; v < NVIEW; ++v) {
            float fx = px[v] * (float)IMG_W - 0.5f;
            float fy = py[v] * (float)IMG_W - 0.5f;
            float xf = floorf(fx), yf = floorf(fy);
            wx[v] = fx - xf;
            wy[v] = fy - yf;
            int x0 = (int)xf;            // in [-1, 799]
            int y0 = (int)yf;
            int xc = min(max(x0, 0), IMG_W - 2);
            int y0i = min(max(y0, 0), IMG_W - 1);
            int y1i = min(y0i + 1, IMG_W - 1);
            hi[v] = (x0 >= IMG_W - 1);
            const float* im = imgs + (size_t)v * IMG_PIX;
            r0[v] = ld2(im + y0i * IMG_W + xc);
            r1[v] = ld2(im + y1i * IMG_W + xc);
        }

        // ---- stage 4: combine ----
        float sval[NVIEW];
#pragma unroll
        for (int v = 0; v < NVIEW; ++v) {
            float v00 = hi[v] ? r0[v].b : r0[v].a;
            float v01 = r0[v].b;
            float v10 = hi[v] ? r1[v].b : r1[v].a;
            float v11 = r1[v].b;
            sval[v] = (v00 * (1.f - wx[v]) + v01 * wx[v]) * (1.f - wy[v])
                    + (v10 * (1.f - wx[v]) + v11 * wx[v]) * wy[v];
        }
        float s1 = sval[0];
        blackf = (s1 < 0.01f) ? 1.f : 0.f;
        float d2[NSRC];
#pragma unroll
        for (int s = 0; s < NSRC; ++s) {
            float d = sval[s + 1] - s1;
            d2[s] = d * d;
            if (!(vm[0] && vm[s + 1]))
                out[NSRC * NEDGE + s * NEDGE + e] = 0.f; // all writers write 0
        }
        d2a = d2[0]; d2b = d2[1]; d2c = d2[2]; d2d = d2[3];
    }

    // wave-level aggregation: consecutive points nearly always share an edge
    int lane = threadIdx.x & 63;
    bool uni = __all(e == __shfl(e, 0));
    if (uni) {
#pragma unroll
        for (int off = 32; off > 0; off >>= 1) {
            d2a += __shfl_down(d2a, off);
            d2b += __shfl_down(d2b, off);
            d2c += __shfl_down(d2c, off);
            d2d += __shfl_down(d2d, off);
            blackf += __shfl_down(blackf, off);
        }
        if (lane == 0 && e >= 0) {
            atomicAdd(&out[0 * NEDGE + e], d2a);
            atomicAdd(&out[1 * NEDGE + e], d2b);
            atomicAdd(&out[2 * NEDGE + e], d2c);
            atomicAdd(&out[3 * NEDGE + e], d2d);
            if (blackf != 0.f) atomicAdd(&out[2 * NSRC * NEDGE + e], blackf);
        }
    } else if (active) {
        atomicAdd(&out[0 * NEDGE + e], d2a);
        atomicAdd(&out[1 * NEDGE + e], d2b);
        atomicAdd(&out[2 * NEDGE + e], d2c);
        atomicAdd(&out[3 * NEDGE + e], d2d);
        if (blackf != 0.f) atomicAdd(&out[2 * NSRC * NEDGE + e], 1.f);
    }
}

// Kernel C: finalize (divide by per-edge count; black-area threshold).
__global__ void finalize_kernel(const int* __restrict__ npe, float* __restrict__ out) {
    int e = blockIdx.x * blockDim.x + threadIdx.x;
    if (e >= NEDGE) return;
    float cnt = (float)npe[e];
#pragma unroll
    for (int s = 0; s < NSRC; ++s)
        out[s * NEDGE + e] = out[s * NEDGE + e] / cnt;
    float bc = out[2 * NSRC * NEDGE + e];
    out[2 * NSRC * NEDGE + e] = (bc / cnt > 0.5f) ? 1.f : 0.f;
}

extern "C" void kernel_launch(void* const* d_in, const int* in_sizes, int n_in,
                              void* d_out, int out_size, void* d_ws, size_t ws_size,
                              hipStream_t stream) {
    const float* start = (const float*)d_in[0];
    const float* endp  = (const float*)d_in[1];
    const float* imgs  = (const float*)d_in[2];
    const float* trans = (const float*)d_in[3];
    const float* K     = (const float*)d_in[4];
    const float* cxs   = (const float*)d_in[5];
    const float* cys   = (const float*)d_in[6];
    const int*   eidx  = (const int*)d_in[7];
    const int*   npe   = (const int*)d_in[8];
    int P = in_sizes[5];

    float4* prm = (float4*)d_ws; // NEDGE*NVIEW*2 float4 = 960 KB

    float* out = (float*)d_out;
    edge_params<<<(NEDGE + 255) / 256, 256, 0, stream>>>(start, endp, K, trans, prm, out);
    points_kernel<<<(P + 255) / 256, 256, 0, stream>>>(cxs, cys, eidx, imgs, prm, out, P);
    finalize_kernel<<<(NEDGE + 255) / 256, 256, 0, stream>>>(npe, out);
}

// Round 3
// 575.574 us; speedup vs baseline: 1.0801x; 1.0131x over previous
//
#include <hip/hip_runtime.h>
#include <math.h>

#define IMG_W   800
#define IMG_PIX (IMG_W * IMG_W)
#define NEDGE   6000
#define NSRC    4
#define NVIEW   5
// d_out layout (floats):
//   sim loss : [0, NSRC*NEDGE)
//   mask     : [NSRC*NEDGE, 2*NSRC*NEDGE)
//   black    : [2*NSRC*NEDGE, 2*NSRC*NEDGE + NEDGE)
//   p2d1     : [HDR, HDR + 2P)
//   p2d2     : [HDR + 2P, HDR + 10P)
#define HDR (2 * NSRC * NEDGE + NEDGE) // 54000

typedef float vf4 __attribute__((ext_vector_type(4)));
typedef float vf2 __attribute__((ext_vector_type(2)));
typedef int   vi4 __attribute__((ext_vector_type(4)));

// 8-byte image-row pair, only 4-byte aligned.
struct __attribute__((packed, aligned(4))) f2u { float a, b; };

__device__ __forceinline__ f2u ld2(const float* __restrict__ p) {
    return *(const f2u*)p;
}
__device__ __forceinline__ void nts2(float* p, float a, float b) {
    vf2 v; v.x = a; v.y = b;
    __builtin_nontemporal_store(v, (vf2*)p);
}
__device__ __forceinline__ void nts4(float* p, float a, float b, float c, float d) {
    vf4 v; v.x = a; v.y = b; v.z = c; v.w = d;
    __builtin_nontemporal_store(v, (vf4*)p);
}

// Kernel A: per-edge, per-view projection params (packed 2x float4 per view);
// also init accumulators/mask in d_out (poisoned 0xAA each launch).
__global__ void edge_params(const float* __restrict__ sp,
                            const float* __restrict__ epnt,
                            const float* __restrict__ K,
                            const float* __restrict__ T,
                            float4* __restrict__ prm,
                            float* __restrict__ out) {
    int e = blockIdx.x * blockDim.x + threadIdx.x;
    if (e >= NEDGE) return;
    float sx = sp[3 * e], sy = sp[3 * e + 1], sz = sp[3 * e + 2];
    float ex = epnt[3 * e], ey = epnt[3 * e + 1], ez = epnt[3 * e + 2];
    for (int v = 0; v < NVIEW; ++v) {
        float as, bs, cs, ae, be, ce;
        if (v == 0) {
            as = K[0] * sx + K[1] * sy + K[2] * sz;
            bs = K[3] * sx + K[4] * sy + K[5] * sz;
            cs = K[6] * sx + K[7] * sy + K[8] * sz;
            ae = K[0] * ex + K[1] * ey + K[2] * ez;
            be = K[3] * ex + K[4] * ey + K[5] * ez;
            ce = K[6] * ex + K[7] * ey + K[8] * ez;
        } else {
            const float* t = T + (v - 1) * 12;
            as = t[0] * sx + t[1] * sy + t[2] * sz + t[3];
            bs = t[4] * sx + t[5] * sy + t[6] * sz + t[7];
            cs = t[8] * sx + t[9] * sy + t[10] * sz + t[11];
            ae = t[0] * ex + t[1] * ey + t[2] * ez + t[3];
            be = t[4] * ex + t[5] * ey + t[6] * ez + t[7];
            ce = t[8] * ex + t[9] * ey + t[10] * ez + t[11];
        }
        float u0 = as / (cs + 1e-6f);
        float w0 = bs / (cs + 1e-6f);
        float u1 = ae / (ce + 1e-6f);
        float w1 = be / (ce + 1e-6f);
        float dx = u1 - u0, dy = w1 - w0;
        float cxx = dy, cyy = -dx;   // cross([dx,dy,0],[0,0,1])
        float nrm = sqrtf(cxx * cxx + cyy * cyy);
        float inv = 1.f / (nrm + 1e-6f) * (10.0f / (float)IMG_W);
        prm[(e * NVIEW + v) * 2 + 0] = make_float4(u0, w0, dx, dy);
        prm[(e * NVIEW + v) * 2 + 1] = make_float4(cxx * inv, cyy * inv, 0.f, 0.f);
    }
    for (int s = 0; s < NSRC; ++s) {
        out[s * NEDGE + e] = 0.f;                // sim loss accum
        out[NSRC * NEDGE + s * NEDGE + e] = 1.f; // mask (segment_min of vm)
    }
    out[2 * NSRC * NEDGE + e] = 0.f;             // black count accum
}

// Kernel B: 4 points per lane; stage all 40 gathers before any consumption.
__global__ void __launch_bounds__(256)
points_kernel(const float* __restrict__ cx,
              const float* __restrict__ cy,
              const int* __restrict__ eidx,
              const float* __restrict__ imgs,
              const float4* __restrict__ prm,
              float* __restrict__ out,
              int P) {
    int t = blockIdx.x * blockDim.x + threadIdx.x;
    int i0 = t * 4;
    int e[4];
    float x[4], y[4];
    bool full = (i0 + 3) < P;
    if (full) {
        vi4 ev = __builtin_nontemporal_load((const vi4*)(eidx + i0));
        vf4 xv = __builtin_nontemporal_load((const vf4*)(cx + i0));
        vf4 yv = __builtin_nontemporal_load((const vf4*)(cy + i0));
        e[0] = ev.x; e[1] = ev.y; e[2] = ev.z; e[3] = ev.w;
        x[0] = xv.x; x[1] = xv.y; x[2] = xv.z; x[3] = xv.w;
        y[0] = yv.x; y[1] = yv.y; y[2] = yv.z; y[3] = yv.w;
    } else {
#pragma unroll
        for (int k = 0; k < 4; ++k) {
            if (i0 + k < P) { e[k] = eidx[i0 + k]; x[k] = cx[i0 + k]; y[k] = cy[i0 + k]; }
            else { e[k] = -1; x[k] = 0.f; y[k] = 0.f; }
        }
    }

    // ---- stage 1: coords for 4 points x 5 views (cache edge params) ----
    float px[4 * NVIEW], py[4 * NVIEW];
    unsigned vmb[4];
    {
        float4 A[NVIEW], B[NVIEW];
        int eld = -1;
#pragma unroll
        for (int k = 0; k < 4; ++k) {
            vmb[k] = 0;
            if (e[k] < 0) continue;
            if (e[k] != eld) {
                const float4* pe = prm + e[k] * (NVIEW * 2);
#pragma unroll
                for (int v = 0; v < NVIEW; ++v) { A[v] = pe[2 * v]; B[v] = pe[2 * v + 1]; }
                eld = e[k];
            }
            unsigned mb = 0;
#pragma unroll
            for (int v = 0; v < NVIEW; ++v) {
                float ux = A[v].z * x[k] + B[v].x * y[k] + A[v].x;
                float uy = A[v].w * x[k] + B[v].y * y[k] + A[v].y;
                if ((ux > 0.f) && (ux < 1.f) && (uy > 0.f) && (uy < 1.f)) mb |= (1u << v);
                px[k * NVIEW + v] = fminf(fmaxf(ux, 0.f), 0.999999f);
                py[k * NVIEW + v] = fminf(fmaxf(uy, 0.f), 0.999999f);
            }
            vmb[k] = mb;
        }
    }

    // ---- stage 2: p2d outputs (non-temporal streaming) ----
    if (full) {
#pragma unroll
        for (int v = 0; v < NVIEW; ++v) {
            float* base = (v == 0) ? (out + HDR + 2 * (size_t)i0)
                                   : (out + HDR + 2 * (size_t)P
                                          + 2 * ((size_t)(v - 1) * P + i0));
            nts4(base,     px[0 * NVIEW + v], py[0 * NVIEW + v],
                           px[1 * NVIEW + v], py[1 * NVIEW + v]);
            nts4(base + 4, px[2 * NVIEW + v], py[2 * NVIEW + v],
                           px[3 * NVIEW + v], py[3 * NVIEW + v]);
        }
    } else {
#pragma unroll
        for (int k = 0; k < 4; ++k) {
            if (e[k] < 0) continue;
            nts2(out + HDR + 2 * (size_t)(i0 + k), px[k * NVIEW], py[k * NVIEW]);
#pragma unroll
            for (int s = 0; s < NSRC; ++s)
                nts2(out + HDR + 2 * (size_t)P + 2 * ((size_t)s * P + i0 + k),
                     px[k * NVIEW + s + 1], py[k * NVIEW + s + 1]);
        }
    }

    // ---- stage 3: issue all 40 row-pair gathers; px/py -> wx/wy in place ----
    f2u r0[4 * NVIEW], r1[4 * NVIEW];
    unsigned hib[4] = {0, 0, 0, 0};
#pragma unroll
    for (int k = 0; k < 4; ++k) {
        if (e[k] < 0) continue;
#pragma unroll
        for (int v = 0; v < NVIEW; ++v) {
            int j = k * NVIEW + v;
            float fx = px[j] * (float)IMG_W - 0.5f;
            float fy = py[j] * (float)IMG_W - 0.5f;
            float xf = floorf(fx), yf = floorf(fy);
            px[j] = fx - xf;                 // wx
            py[j] = fy - yf;                 // wy
            int x0 = (int)xf;                // in [-1, 799]
            int y0 = (int)yf;
            int xc = min(max(x0, 0), IMG_W - 2);
            int y0i = min(max(y0, 0), IMG_W - 1);
            int y1i = min(y0i + 1, IMG_W - 1);
            if (x0 >= IMG_W - 1) hib[k] |= (1u << v);
            const float* im = imgs + v * IMG_PIX;
            r0[j] = ld2(im + y0i * IMG_W + xc);
            r1[j] = ld2(im + y1i * IMG_W + xc);
        }
    }

    // ---- stage 4: combine + per-lane accumulate (strays -> direct atomics) ----
    float accs[NSRC] = {0.f, 0.f, 0.f, 0.f};
    float accB = 0.f;
#pragma unroll
    for (int k = 0; k < 4; ++k) {
        if (e[k] < 0) continue;
        float sval[NVIEW];
#pragma unroll
        for (int v = 0; v < NVIEW; ++v) {
            int j = k * NVIEW + v;
            bool hi = (hib[k] >> v) & 1u;
            float v00 = hi ? r0[j].b : r0[j].a;
            float v01 = r0[j].b;
            float v10 = hi ? r1[j].b : r1[j].a;
            float v11 = r1[j].b;
            float wxv = px[j], wyv = py[j];
            sval[v] = (v00 * (1.f - wxv) + v01 * wxv) * (1.f - wyv)
                    + (v10 * (1.f - wxv) + v11 * wxv) * wyv;
        }
        float s1 = sval[0];
        float blk = (s1 < 0.01f) ? 1.f : 0.f;
        bool same = (e[k] == e[0]);
        if (same) accB += blk;
        else if (blk != 0.f) atomicAdd(&out[2 * NSRC * NEDGE + e[k]], blk);
        bool vm1 = vmb[k] & 1u;
#pragma unroll
        for (int s = 0; s < NSRC; ++s) {
            float d = sval[s + 1] - s1;
            float dd = d * d;
            if (!(vm1 && ((vmb[k] >> (s + 1)) & 1u)))
                out[NSRC * NEDGE + s * NEDGE + e[k]] = 0.f; // all writers write 0
            if (same) accs[s] += dd;
            else atomicAdd(&out[s * NEDGE + e[k]], dd);
        }
    }

    // ---- wave aggregation over the e[0]-group ----
    int e0 = e[0];
    bool laneU = full && (e[0] == e[3]);
    bool uni = __all(laneU && (e0 == __shfl(e0, 0)));
    int lane = threadIdx.x & 63;
    if (uni) {
#pragma unroll
        for (int off = 32; off > 0; off >>= 1) {
            accs[0] += __shfl_down(accs[0], off);
            accs[1] += __shfl_down(accs[1], off);
            accs[2] += __shfl_down(accs[2], off);
            accs[3] += __shfl_down(accs[3], off);
            accB    += __shfl_down(accB, off);
        }
        if (lane == 0) {
            atomicAdd(&out[0 * NEDGE + e0], accs[0]);
            atomicAdd(&out[1 * NEDGE + e0], accs[1]);
            atomicAdd(&out[2 * NEDGE + e0], accs[2]);
            atomicAdd(&out[3 * NEDGE + e0], accs[3]);
            if (accB != 0.f) atomicAdd(&out[2 * NSRC * NEDGE + e0], accB);
        }
    } else if (e0 >= 0) {
        atomicAdd(&out[0 * NEDGE + e0], accs[0]);
        atomicAdd(&out[1 * NEDGE + e0], accs[1]);
        atomicAdd(&out[2 * NEDGE + e0], accs[2]);
        atomicAdd(&out[3 * NEDGE + e0], accs[3]);
        if (accB != 0.f) atomicAdd(&out[2 * NSRC * NEDGE + e0], accB);
    }
}

// Kernel C: finalize (divide by per-edge count; black-area threshold).
__global__ void finalize_kernel(const int* __restrict__ npe, float* __restrict__ out) {
    int e = blockIdx.x * blockDim.x + threadIdx.x;
    if (e >= NEDGE) return;
    float cnt = (float)npe[e];
#pragma unroll
    for (int s = 0; s < NSRC; ++s)
        out[s * NEDGE + e] = out[s * NEDGE + e] / cnt;
    float bc = out[2 * NSRC * NEDGE + e];
    out[2 * NSRC * NEDGE + e] = (bc / cnt > 0.5f) ? 1.f : 0.f;
}

extern "C" void kernel_launch(void* const* d_in, const int* in_sizes, int n_in,
                              void* d_out, int out_size, void* d_ws, size_t ws_size,
                              hipStream_t stream) {
    const float* start = (const float*)d_in[0];
    const float* endp  = (const float*)d_in[1];
    const float* imgs  = (const float*)d_in[2];
    const float* trans = (const float*)d_in[3];
    const float* K     = (const float*)d_in[4];
    const float* cxs   = (const float*)d_in[5];
    const float* cys   = (const float*)d_in[6];
    const int*   eidx  = (const int*)d_in[7];
    const int*   npe   = (const int*)d_in[8];
    int P = in_sizes[5];

    float4* prm = (float4*)d_ws; // NEDGE*NVIEW*2 float4 = 960 KB

    float* out = (float*)d_out;
    edge_params<<<(NEDGE + 255) / 256, 256, 0, stream>>>(start, endp, K, trans, prm, out);
    int nthread = (P + 3) / 4;
    points_kernel<<<(nthread + 255) / 256, 256, 0, stream>>>(cxs, cys, eidx, imgs, prm, out, P);
    finalize_kernel<<<(NEDGE + 255) / 256, 256, 0, stream>>>(npe, out);
}